// Round 11
// baseline (157.918 us; speedup 1.0000x reference)
//
#include <hip/hip_runtime.h>
#include <math.h>

// Problem constants (match reference)
constexpr int   B       = 2048;
constexpr int   P       = 4;
constexpr int   D       = 256;       // K of the GEMM
constexpr int   NNEG    = 32768;
constexpr int   NT      = NNEG / 32; // 1024 per-row exp2-sum partials (32-col patches)
constexpr float TEMP    = 0.05f;
constexpr float ALPHA   = 0.1f;
constexpr float EPS     = 1e-12f;
constexpr float INV_T   = 1.0f / TEMP;
// A-side rows are pre-scaled by (1/T)*log2(e) so the MFMA accumulator is
// directly q = sim/T * log2(e), and exp(sim/T) = exp2(q).  |q| <= ~30 so no
// max-tracking is needed (exp2 stays in fp32 range).
constexpr float SCALE_Q = 28.853900817779268f;

typedef __bf16 bf16x8 __attribute__((ext_vector_type(8)));
typedef float  f32x4  __attribute__((ext_vector_type(4)));

// fp32 -> bf16 (RNE), bit-level
__device__ inline unsigned short f2bf(float f) {
  unsigned int u = __float_as_uint(f);
  u = (u + 0x7fffu + ((u >> 16) & 1u)) >> 16;
  return (unsigned short)u;
}

// ---------------------------------------------------------------------------
// FRAGMENT-MAJOR layout (16-row panels, verified rounds 7-9): element (row,k)
// of a [R x 256] bf16 matrix lives at ushort index
//   p*4096 + c*512 + q*128 + r*8 + j
// where p=row>>4, r=row&15, c=k>>5, q=(k>>3)&3, j=k&7.
// Fragment (p,c) = 1024 contiguous bytes; MFMA lane l=r+16q reads its 16 B at
// byte offset l*16 -> one coalesced global_load_dwordx4 per fragment, and
// global_load_lds staging is exactly lane-contiguous.
// k is identically permuted for A and B, so the dot product is unchanged.
// ---------------------------------------------------------------------------

// ---------------------------------------------------------------------------
// Kernel 1 (fused prep): one wave per work row (identical to round 9).
//   rows [0, B)         : normalize anchor, scale SCALE_Q, cast bf16 -> frag-major
//   rows [B, B+NNEG)    : normalize negative, cast bf16 -> frag-major
//   rows [B+NNEG,+B*P)  : pos_sim pair dot (exact fp32)
// ---------------------------------------------------------------------------
__global__ void prep_kernel(const float* __restrict__ a,
                            const float* __restrict__ pzx,
                            const float* __restrict__ n,
                            unsigned short* __restrict__ a_bf,
                            unsigned short* __restrict__ n_bf,
                            float* __restrict__ pos_sim,
                            float* __restrict__ loss_acc,
                            unsigned int* __restrict__ ticket) {
  if (blockIdx.x == 0 && threadIdx.x == 0) { *loss_acc = 0.0f; *ticket = 0u; }
  int w    = (blockIdx.x * blockDim.x + threadIdx.x) >> 6;
  int lane = threadIdx.x & 63;
  if (w < B + NNEG) {
    const float* src; unsigned short* dstm; int row; float post;
    if (w < B) { src = a + (size_t)w * D;       dstm = a_bf; row = w;     post = SCALE_Q; }
    else       { src = n + (size_t)(w - B) * D; dstm = n_bf; row = w - B; post = 1.0f; }
    float4 v = ((const float4*)src)[lane];
    float ss = v.x * v.x + v.y * v.y + v.z * v.z + v.w * v.w;
#pragma unroll
    for (int off = 32; off > 0; off >>= 1) ss += __shfl_xor(ss, off, 64);
    float inv = post / fmaxf(sqrtf(ss), EPS);
    ushort4 o;
    o.x = f2bf(v.x * inv); o.y = f2bf(v.y * inv);
    o.z = f2bf(v.z * inv); o.w = f2bf(v.w * inv);
    const int p = row >> 4, r = row & 15;
    const int c = lane >> 3, q = (lane >> 1) & 3, j0 = (lane & 1) * 4;
    *(ushort4*)(dstm + (size_t)p * 4096 + c * 512 + q * 128 + r * 8 + j0) = o;
  } else {
    int pw = w - (B + NNEG);           // 0..B*P-1
    if (pw >= B * P) return;
    int b = pw >> 2;                   // P == 4
    float4 av = ((const float4*)(a + (size_t)b * D))[lane];
    float4 pv = ((const float4*)(pzx + (size_t)pw * D))[lane];
    float d  = av.x * pv.x + av.y * pv.y + av.z * pv.z + av.w * pv.w;
    float sa = av.x * av.x + av.y * av.y + av.z * av.z + av.w * av.w;
    float sp = pv.x * pv.x + pv.y * pv.y + pv.z * pv.z + pv.w * pv.w;
#pragma unroll
    for (int off = 32; off > 0; off >>= 1) {
      d  += __shfl_xor(d, off, 64);
      sa += __shfl_xor(sa, off, 64);
      sp += __shfl_xor(sp, off, 64);
    }
    if (lane == 0) {
      float inva = 1.0f / fmaxf(sqrtf(sa), EPS);
      float invp = 1.0f / fmaxf(sqrtf(sp), EPS);
      pos_sim[pw] = d * inva * invp * INV_T;
    }
  }
}

// ---------------------------------------------------------------------------
// Kernel 2: bf16 MFMA GEMM (16x16x32, the proven shape) fused with exp2-sum
// partials.
//
// Round-11 change vs round 9: same 64x256 block tile, but EIGHT waves (512
// threads); wave w owns a 64x32 col-patch (4x2 of 16x16 tiles, acc = 8 x
// f32x4 = 32 VGPR).  Total regs/wave ~80 -> 6 waves/SIMD
// (__launch_bounds__(512,6)) = 24 waves/CU vs round 9's 16 — per-SIMD
// round-robin now covers the ~200 cyc L2 latency of the depth-1 B ping-pong
// (6 waves x ~39 cyc/chunk of MFMA issue ≈ 234 cyc).
//
// A-tile (64 rows x 256 k = 32 frags = 32 KB) staged into LDS ONCE via
// global_load_lds (4 frags/wave), then the kernel's ONLY barrier; zero
// barriers in the K-loop.  B fragments depth-1 ping-pong direct from
// frag-major global (named arrays under full unroll = SSA, no scratch).
// 32x32x16 shape was tried (round 10) and REGRESSED: only 4 acc chains of
// 8-cyc MFMAs -> dependent-latency stalls; 16x16x32 keeps 8 chains here.
//
// XCD swizzle: id&7 -> xcd owns a 16-nblk strip (2 MB of N) + all of A
// (1 MB) < 4 MB per-XCD L2.
//
// Epilogue: acc holds q = sim/T*log2e; per row, sum exp2(q) over the wave's
// 32 cols via 16-lane shuffle reduce -> part_s[row][nblk*8+wave].
// ---------------------------------------------------------------------------
constexpr int BM = 64, BN = 256;

__global__ __launch_bounds__(512, 6) void negsim_mfma_kernel(
    const unsigned short* __restrict__ Af,   // frag-major [B][256]
    const unsigned short* __restrict__ Nf,   // frag-major [NNEG][256]
    float* __restrict__ part_s) {            // [B][NT]
  // 32 fragments x 512 ushorts = 32 KB; frag (panel p, chunk c) at (c*4+p)*512
  __shared__ __align__(16) unsigned short As[32 * 512];

  const int tid  = threadIdx.x;
  const int wave = tid >> 6;   // 0..7 = N-direction 32-col patch
  const int lane = tid & 63;

  // XCD-aware decode of flat block id (4096 blocks)
  const int id   = blockIdx.x;
  const int xcd  = id & 7;
  const int j    = id >> 3;              // 0..511
  const int nblk = xcd * 16 + (j & 15);  // 0..127
  const int mblk = j >> 4;               // 0..31
  const int m0   = mblk * BM;
  const int n0   = nblk * BN;

  // ---- stage A-tile (32 frags) once: wave stages frags [wave*4, +4) ----
#pragma unroll
  for (int t = 0; t < 4; t++) {
    const int f = wave * 4 + t;        // 0..31
    const int c = f >> 2, p = f & 3;
    __builtin_amdgcn_global_load_lds(
        (const __attribute__((address_space(1))) unsigned int*)
            (Af + (size_t)((m0 >> 4) + p) * 4096 + c * 512 + lane * 8),
        (__attribute__((address_space(3))) unsigned int*)(As + f * 512 + lane * 8),
        16, 0, 0);
  }
  __syncthreads();   // the kernel's only barrier (drains the staging loads)

  // ---- K-loop: A from LDS, B ping-pong direct from global ----
  // wave covers cols [n0 + wave*32, +32) -> panels (n0>>4) + wave*2 + ni
  const unsigned short* Bp = Nf + (size_t)((n0 >> 4) + wave * 2) * 4096 + lane * 8;

  f32x4 acc[4][2] = {};   // [mi][ni]
  bf16x8 b0[2], b1[2];

#pragma unroll
  for (int ni = 0; ni < 2; ni++)
    b0[ni] = *(const bf16x8*)(Bp + (size_t)ni * 4096);

#pragma unroll
  for (int c = 0; c < 8; c += 2) {
    // prefetch chunk c+1 (c even, c+1 <= 7 always exists)
#pragma unroll
    for (int ni = 0; ni < 2; ni++)
      b1[ni] = *(const bf16x8*)(Bp + (size_t)ni * 4096 + (c + 1) * 512);
    {
      bf16x8 af[4];
#pragma unroll
      for (int mi = 0; mi < 4; mi++)
        af[mi] = *(const bf16x8*)&As[(c * 4 + mi) * 512 + lane * 8];
#pragma unroll
      for (int mi = 0; mi < 4; mi++)
#pragma unroll
        for (int ni = 0; ni < 2; ni++)
          acc[mi][ni] = __builtin_amdgcn_mfma_f32_16x16x32_bf16(
              af[mi], b0[ni], acc[mi][ni], 0, 0, 0);
    }
    if (c + 2 < 8) {
#pragma unroll
      for (int ni = 0; ni < 2; ni++)
        b0[ni] = *(const bf16x8*)(Bp + (size_t)ni * 4096 + (c + 2) * 512);
    }
    {
      bf16x8 af[4];
#pragma unroll
      for (int mi = 0; mi < 4; mi++)
        af[mi] = *(const bf16x8*)&As[((c + 1) * 4 + mi) * 512 + lane * 8];
#pragma unroll
      for (int mi = 0; mi < 4; mi++)
#pragma unroll
        for (int ni = 0; ni < 2; ni++)
          acc[mi][ni] = __builtin_amdgcn_mfma_f32_16x16x32_bf16(
              af[mi], b1[ni], acc[mi][ni], 0, 0, 0);
    }
  }

  // Epilogue: C/D layout row = mi*16 + (lane>>4)*4 + rr, col = ni*16+(lane&15).
#pragma unroll
  for (int mi = 0; mi < 4; mi++) {
#pragma unroll
    for (int rr = 0; rr < 4; rr++) {
      float s = __builtin_amdgcn_exp2f(acc[mi][0][rr]) +
                __builtin_amdgcn_exp2f(acc[mi][1][rr]);
#pragma unroll
      for (int off = 1; off < 16; off <<= 1) s += __shfl_xor(s, off, 64);
      if ((lane & 15) == 0) {
        int row = m0 + mi * 16 + (lane >> 4) * 4 + rr;
        part_s[(size_t)row * NT + (nblk * 8 + wave)] = s;
      }
    }
  }
}

// ---------------------------------------------------------------------------
// Kernel 3: per-anchor loss + final reduce.  128 blocks x 256 threads; each
// 16-lane group handles one anchor (16-way split of the 1024-partial sum).
// One atomicAdd per block (128 total) + ticket; last block writes out[0].
// ---------------------------------------------------------------------------
__global__ void loss_kernel(const float* __restrict__ part_s,
                            const float* __restrict__ pos_sim,
                            const int* __restrict__ counts,
                            float* __restrict__ loss_acc,
                            unsigned int* __restrict__ ticket,
                            float* __restrict__ out) {
  const int tid = threadIdx.x;
  const int b   = blockIdx.x * 16 + (tid >> 4);
  const int sub = tid & 15;
  const float* ps = part_s + (size_t)b * NT;
  float s = 0.0f;
#pragma unroll
  for (int i = 0; i < NT / 16; i++) s += ps[sub + i * 16];
  s += __shfl_xor(s, 1, 64);
  s += __shfl_xor(s, 2, 64);
  s += __shfl_xor(s, 4, 64);
  s += __shfl_xor(s, 8, 64);   // 16-lane group now holds full S

  float acc = 0.0f;
  if (sub == 0) {
    float L = logf(s);  // neg_lse in natural-log units
    float p0 = pos_sim[b * P + 0], p1 = pos_sim[b * P + 1];
    float p2 = pos_sim[b * P + 2], p3 = pos_sim[b * P + 3];
    int cnt = counts[b];
    float pj[P] = {p0, p1, p2, p3};
#pragma unroll
    for (int jj = 0; jj < P; jj++) {
      if (jj < cnt) {
        float hi = fmaxf(pj[jj], L), lo = fminf(pj[jj], L);
        acc += hi + log1pf(__expf(lo - hi)) - pj[jj];
      }
    }
    float mp = fmaxf(fmaxf(p0, p1), fmaxf(p2, p3));
    float e0 = __expf(p0 - mp), e1 = __expf(p1 - mp);
    float e2 = __expf(p2 - mp), e3 = __expf(p3 - mp);
    float se = e0 + e1 + e2 + e3;
    float wps = (e0 * p0 + e1 * p1 + e2 * p2 + e3 * p3) / se;
    if (cnt > 1) {
      float hi = fmaxf(wps, L), lo = fminf(wps, L);
      acc += ALPHA * (hi + log1pf(__expf(lo - hi)) - wps);
    }
  }
  // block reduce (only sub==0 lanes carry nonzero)
#pragma unroll
  for (int off = 32; off > 0; off >>= 1) acc += __shfl_xor(acc, off, 64);
  __shared__ float sa[4];
  int wid = tid >> 6, lane = tid & 63;
  if (lane == 0) sa[wid] = acc;
  __syncthreads();
  if (tid == 0) {
    atomicAdd(loss_acc, sa[0] + sa[1] + sa[2] + sa[3]);
    __threadfence();
    unsigned int t = atomicAdd(ticket, 1u);
    if (t == (unsigned int)gridDim.x - 1u) {
      float total = atomicAdd(loss_acc, 0.0f);  // atomic read-back
      out[0] = total / (float)B;
    }
  }
}

// ---------------------------------------------------------------------------
extern "C" void kernel_launch(void* const* d_in, const int* in_sizes, int n_in,
                              void* d_out, int out_size, void* d_ws,
                              size_t ws_size, hipStream_t stream) {
  const float* anc    = (const float*)d_in[0];
  const float* pos    = (const float*)d_in[1];
  const float* neg    = (const float*)d_in[2];
  const int*   counts = (const int*)d_in[3];
  float* out = (float*)d_out;

  // Workspace layout: ~25.1 MB (same budget as round 2, known-good)
  unsigned short* a_bf = (unsigned short*)d_ws;          // B*D      (1 MB)
  unsigned short* n_bf = a_bf + (size_t)B * D;           // NNEG*D   (16 MB)
  float* part_s  = (float*)(n_bf + (size_t)NNEG * D);    // B*NT     (8 MB)
  float* pos_sim = part_s + (size_t)B * NT;              // B*P
  float* loss_acc = pos_sim + B * P;                     // 1
  unsigned int* ticket = (unsigned int*)(loss_acc + 1);  // 1

  // 43008 work-rows (norm-cast B+NNEG, possim B*P), 4 waves/block
  prep_kernel<<<(B + NNEG + B * P) / 4, 256, 0, stream>>>(
      anc, pos, neg, a_bf, n_bf, pos_sim, loss_acc, ticket);

  negsim_mfma_kernel<<<4096, 512, 0, stream>>>(a_bf, n_bf, part_s);

  loss_kernel<<<B / 16, 256, 0, stream>>>(part_s, pos_sim, counts,
                                          loss_acc, ticket, out);
}

// Round 12
// 138.302 us; speedup vs baseline: 1.1418x; 1.1418x over previous
//
#include <hip/hip_runtime.h>
#include <math.h>

// Problem constants (match reference)
constexpr int   B       = 2048;
constexpr int   P       = 4;
constexpr int   D       = 256;       // K of the GEMM
constexpr int   NNEG    = 32768;
constexpr int   NTILES  = NNEG / 64; // per-row exp2-sum partials (64-col patches)
constexpr float TEMP    = 0.05f;
constexpr float ALPHA   = 0.1f;
constexpr float EPS     = 1e-12f;
constexpr float INV_T   = 1.0f / TEMP;
// A-side rows are pre-scaled by (1/T)*log2(e) so the MFMA accumulator is
// directly q = sim/T * log2(e), and exp(sim/T) = exp2(q).  |q| <= ~30 so no
// max-tracking is needed (exp2 stays in fp32 range).
constexpr float SCALE_Q = 28.853900817779268f;

typedef __bf16 bf16x8 __attribute__((ext_vector_type(8)));
typedef float  f32x4  __attribute__((ext_vector_type(4)));

// fp32 -> bf16 (RNE), bit-level
__device__ inline unsigned short f2bf(float f) {
  unsigned int u = __float_as_uint(f);
  u = (u + 0x7fffu + ((u >> 16) & 1u)) >> 16;
  return (unsigned short)u;
}

// ---------------------------------------------------------------------------
// FRAGMENT-MAJOR layout (16-row panels, verified rounds 7-9): element (row,k)
// of a [R x 256] bf16 matrix lives at ushort index
//   p*4096 + c*512 + q*128 + r*8 + j
// where p=row>>4, r=row&15, c=k>>5, q=(k>>3)&3, j=k&7.
// Fragment (p,c) = 1024 contiguous bytes; MFMA lane l=r+16q reads its 16 B at
// byte offset l*16 -> one coalesced global_load_dwordx4 per fragment, and
// global_load_lds staging is exactly lane-contiguous.
// k is identically permuted for A and B, so the dot product is unchanged.
// ---------------------------------------------------------------------------

// ---------------------------------------------------------------------------
// Kernel 1 (fused prep): one wave per work row (identical to round 9).
//   rows [0, B)         : normalize anchor, scale SCALE_Q, cast bf16 -> frag-major
//   rows [B, B+NNEG)    : normalize negative, cast bf16 -> frag-major
//   rows [B+NNEG,+B*P)  : pos_sim pair dot (exact fp32)
// ---------------------------------------------------------------------------
__global__ void prep_kernel(const float* __restrict__ a,
                            const float* __restrict__ pzx,
                            const float* __restrict__ n,
                            unsigned short* __restrict__ a_bf,
                            unsigned short* __restrict__ n_bf,
                            float* __restrict__ pos_sim,
                            float* __restrict__ loss_acc,
                            unsigned int* __restrict__ ticket) {
  if (blockIdx.x == 0 && threadIdx.x == 0) { *loss_acc = 0.0f; *ticket = 0u; }
  int w    = (blockIdx.x * blockDim.x + threadIdx.x) >> 6;
  int lane = threadIdx.x & 63;
  if (w < B + NNEG) {
    const float* src; unsigned short* dstm; int row; float post;
    if (w < B) { src = a + (size_t)w * D;       dstm = a_bf; row = w;     post = SCALE_Q; }
    else       { src = n + (size_t)(w - B) * D; dstm = n_bf; row = w - B; post = 1.0f; }
    float4 v = ((const float4*)src)[lane];
    float ss = v.x * v.x + v.y * v.y + v.z * v.z + v.w * v.w;
#pragma unroll
    for (int off = 32; off > 0; off >>= 1) ss += __shfl_xor(ss, off, 64);
    float inv = post / fmaxf(sqrtf(ss), EPS);
    ushort4 o;
    o.x = f2bf(v.x * inv); o.y = f2bf(v.y * inv);
    o.z = f2bf(v.z * inv); o.w = f2bf(v.w * inv);
    const int p = row >> 4, r = row & 15;
    const int c = lane >> 3, q = (lane >> 1) & 3, j0 = (lane & 1) * 4;
    *(ushort4*)(dstm + (size_t)p * 4096 + c * 512 + q * 128 + r * 8 + j0) = o;
  } else {
    int pw = w - (B + NNEG);           // 0..B*P-1
    if (pw >= B * P) return;
    int b = pw >> 2;                   // P == 4
    float4 av = ((const float4*)(a + (size_t)b * D))[lane];
    float4 pv = ((const float4*)(pzx + (size_t)pw * D))[lane];
    float d  = av.x * pv.x + av.y * pv.y + av.z * pv.z + av.w * pv.w;
    float sa = av.x * av.x + av.y * av.y + av.z * av.z + av.w * av.w;
    float sp = pv.x * pv.x + pv.y * pv.y + pv.z * pv.z + pv.w * pv.w;
#pragma unroll
    for (int off = 32; off > 0; off >>= 1) {
      d  += __shfl_xor(d, off, 64);
      sa += __shfl_xor(sa, off, 64);
      sp += __shfl_xor(sp, off, 64);
    }
    if (lane == 0) {
      float inva = 1.0f / fmaxf(sqrtf(sa), EPS);
      float invp = 1.0f / fmaxf(sqrtf(sp), EPS);
      pos_sim[pw] = d * inva * invp * INV_T;
    }
  }
}

// ---------------------------------------------------------------------------
// Kernel 2: bf16 MFMA GEMM (16x16x32) fused with exp2-sum partials.
// ROUND-9 STRUCTURE (proven 44 us) + DEPTH-2 B PREFETCH (the only change):
//
// Block = 64 x 256 tile, 4 waves; wave w owns the 64x64 col-patch (4x4 of
// 16x16 tiles, acc = 16 x f32x4 = 64 AGPR).  A-tile (64 rows x 256 k =
// 32 frags = 32 KB) staged into LDS ONCE via global_load_lds, then the
// kernel's ONLY barrier; zero barriers in the K-loop.  B fragments come
// DEPTH-2 rotated (3 named buffers, constant indices under full unroll =
// SSA, no scratch — R10 proved the rotation mechanism is spill-free).
// Issue-to-use distance ~2 compute phases (~600 SIMD-cyc) >> ~200 cyc L2
// latency: the wave decouples from L2 even at 3 waves/SIMD.  R11 proved
// more occupancy does NOT help (52% occ -> slower), so we spend registers
// on prefetch depth instead: launch_bounds(256,3) (B bufs 48 + acc 64 +
// af 16 + addr ~ 135 unified regs; forcing 4 waves/SIMD would spill).
//
// XCD swizzle: id&7 -> xcd owns a 16-nblk strip (2 MB of N) + all of A
// (1 MB) < 4 MB per-XCD L2.
//
// Epilogue: acc holds q = sim/T*log2e; per row, sum exp2(q) over the wave's
// 64 cols via 16-lane shuffle reduce -> part_s[row][nblk*4+wave].
// ---------------------------------------------------------------------------
constexpr int BM = 64, BN = 256;

__global__ __launch_bounds__(256, 3) void negsim_mfma_kernel(
    const unsigned short* __restrict__ Af,   // frag-major [B][256]
    const unsigned short* __restrict__ Nf,   // frag-major [NNEG][256]
    float* __restrict__ part_s) {            // [B][NTILES]
  // 32 fragments x 512 ushorts = 32 KB; frag (panel p, chunk c) at (c*4+p)*512
  __shared__ __align__(16) unsigned short As[32 * 512];

  const int tid  = threadIdx.x;
  const int wave = tid >> 6;   // 0..3 = N-direction 64-col patch
  const int lane = tid & 63;

  // XCD-aware decode of flat block id (4096 blocks)
  const int id   = blockIdx.x;
  const int xcd  = id & 7;
  const int j    = id >> 3;              // 0..511
  const int nblk = xcd * 16 + (j & 15);  // 0..127
  const int mblk = j >> 4;               // 0..31
  const int m0   = mblk * BM;
  const int n0   = nblk * BN;

  // ---- stage A-tile (32 frags) once: wave stages frags [wave*8, +8) ----
#pragma unroll
  for (int t = 0; t < 8; t++) {
    const int f = wave * 8 + t;        // 0..31
    const int c = f >> 2, p = f & 3;
    __builtin_amdgcn_global_load_lds(
        (const __attribute__((address_space(1))) unsigned int*)
            (Af + (size_t)((m0 >> 4) + p) * 4096 + c * 512 + lane * 8),
        (__attribute__((address_space(3))) unsigned int*)(As + f * 512 + lane * 8),
        16, 0, 0);
  }
  __syncthreads();   // the kernel's only barrier (drains the staging loads)

  // ---- K-loop: A from LDS, B depth-2 rotation direct from global ----
  const unsigned short* Bp = Nf + (size_t)((n0 >> 4) + wave * 4) * 4096 + lane * 8;

  f32x4 acc[4][4] = {};   // [mi][ni]
  bf16x8 bb[3][4];        // depth-2 rotation; constant-indexed under unroll

#pragma unroll
  for (int ni = 0; ni < 4; ni++) {
    bb[0][ni] = *(const bf16x8*)(Bp + (size_t)ni * 4096 + 0 * 512);
    bb[1][ni] = *(const bf16x8*)(Bp + (size_t)ni * 4096 + 1 * 512);
  }

#pragma unroll
  for (int c = 0; c < 8; c++) {
    if (c + 2 < 8) {
#pragma unroll
      for (int ni = 0; ni < 4; ni++)
        bb[(c + 2) % 3][ni] =
            *(const bf16x8*)(Bp + (size_t)ni * 4096 + (c + 2) * 512);
    }
    bf16x8 af[4];
#pragma unroll
    for (int mi = 0; mi < 4; mi++)
      af[mi] = *(const bf16x8*)&As[(c * 4 + mi) * 512 + lane * 8];
#pragma unroll
    for (int mi = 0; mi < 4; mi++)
#pragma unroll
      for (int ni = 0; ni < 4; ni++)
        acc[mi][ni] = __builtin_amdgcn_mfma_f32_16x16x32_bf16(
            af[mi], bb[c % 3][ni], acc[mi][ni], 0, 0, 0);
  }

  // Epilogue: C/D layout row = mi*16 + (lane>>4)*4 + rr, col = ni*16+(lane&15).
#pragma unroll
  for (int mi = 0; mi < 4; mi++) {
#pragma unroll
    for (int rr = 0; rr < 4; rr++) {
      float s = __builtin_amdgcn_exp2f(acc[mi][0][rr]) +
                __builtin_amdgcn_exp2f(acc[mi][1][rr]) +
                __builtin_amdgcn_exp2f(acc[mi][2][rr]) +
                __builtin_amdgcn_exp2f(acc[mi][3][rr]);
#pragma unroll
      for (int off = 1; off < 16; off <<= 1) s += __shfl_xor(s, off, 64);
      if ((lane & 15) == 0) {
        int row = m0 + mi * 16 + (lane >> 4) * 4 + rr;
        part_s[(size_t)row * NTILES + (nblk * 4 + wave)] = s;
      }
    }
  }
}

// ---------------------------------------------------------------------------
// Kernel 3: per-anchor loss + final reduce.  128 blocks x 256 threads; each
// 16-lane group handles one anchor (16-way split of the 512-partial sum).
// One atomicAdd per block (128 total) + ticket; last block writes out[0].
// ---------------------------------------------------------------------------
__global__ void loss_kernel(const float* __restrict__ part_s,
                            const float* __restrict__ pos_sim,
                            const int* __restrict__ counts,
                            float* __restrict__ loss_acc,
                            unsigned int* __restrict__ ticket,
                            float* __restrict__ out) {
  const int tid = threadIdx.x;
  const int b   = blockIdx.x * 16 + (tid >> 4);
  const int sub = tid & 15;
  const float* ps = part_s + (size_t)b * NTILES;
  float s = 0.0f;
#pragma unroll
  for (int i = 0; i < NTILES / 16; i++) s += ps[sub + i * 16];
  s += __shfl_xor(s, 1, 64);
  s += __shfl_xor(s, 2, 64);
  s += __shfl_xor(s, 4, 64);
  s += __shfl_xor(s, 8, 64);   // 16-lane group now holds full S

  float acc = 0.0f;
  if (sub == 0) {
    float L = logf(s);  // neg_lse in natural-log units
    float p0 = pos_sim[b * P + 0], p1 = pos_sim[b * P + 1];
    float p2 = pos_sim[b * P + 2], p3 = pos_sim[b * P + 3];
    int cnt = counts[b];
    float pj[P] = {p0, p1, p2, p3};
#pragma unroll
    for (int jj = 0; jj < P; jj++) {
      if (jj < cnt) {
        float hi = fmaxf(pj[jj], L), lo = fminf(pj[jj], L);
        acc += hi + log1pf(__expf(lo - hi)) - pj[jj];
      }
    }
    float mp = fmaxf(fmaxf(p0, p1), fmaxf(p2, p3));
    float e0 = __expf(p0 - mp), e1 = __expf(p1 - mp);
    float e2 = __expf(p2 - mp), e3 = __expf(p3 - mp);
    float se = e0 + e1 + e2 + e3;
    float wps = (e0 * p0 + e1 * p1 + e2 * p2 + e3 * p3) / se;
    if (cnt > 1) {
      float hi = fmaxf(wps, L), lo = fminf(wps, L);
      acc += ALPHA * (hi + log1pf(__expf(lo - hi)) - wps);
    }
  }
  // block reduce (only sub==0 lanes carry nonzero)
#pragma unroll
  for (int off = 32; off > 0; off >>= 1) acc += __shfl_xor(acc, off, 64);
  __shared__ float sa[4];
  int wid = tid >> 6, lane = tid & 63;
  if (lane == 0) sa[wid] = acc;
  __syncthreads();
  if (tid == 0) {
    atomicAdd(loss_acc, sa[0] + sa[1] + sa[2] + sa[3]);
    __threadfence();
    unsigned int t = atomicAdd(ticket, 1u);
    if (t == (unsigned int)gridDim.x - 1u) {
      float total = atomicAdd(loss_acc, 0.0f);  // atomic read-back
      out[0] = total / (float)B;
    }
  }
}

// ---------------------------------------------------------------------------
extern "C" void kernel_launch(void* const* d_in, const int* in_sizes, int n_in,
                              void* d_out, int out_size, void* d_ws,
                              size_t ws_size, hipStream_t stream) {
  const float* anc    = (const float*)d_in[0];
  const float* pos    = (const float*)d_in[1];
  const float* neg    = (const float*)d_in[2];
  const int*   counts = (const int*)d_in[3];
  float* out = (float*)d_out;

  // Workspace layout: ~21.1 MB
  unsigned short* a_bf = (unsigned short*)d_ws;          // B*D      (1 MB)
  unsigned short* n_bf = a_bf + (size_t)B * D;           // NNEG*D   (16 MB)
  float* part_s  = (float*)(n_bf + (size_t)NNEG * D);    // B*NTILES (4 MB)
  float* pos_sim = part_s + (size_t)B * NTILES;          // B*P
  float* loss_acc = pos_sim + B * P;                     // 1
  unsigned int* ticket = (unsigned int*)(loss_acc + 1);  // 1

  // 43008 work-rows (norm-cast B+NNEG, possim B*P), 4 waves/block
  prep_kernel<<<(B + NNEG + B * P) / 4, 256, 0, stream>>>(
      anc, pos, neg, a_bf, n_bf, pos_sim, loss_acc, ticket);

  negsim_mfma_kernel<<<4096, 256, 0, stream>>>(a_bf, n_bf, part_s);

  loss_kernel<<<B / 16, 256, 0, stream>>>(part_s, pos_sim, counts,
                                          loss_acc, ticket, out);
}

// Round 13
// 137.428 us; speedup vs baseline: 1.1491x; 1.0064x over previous
//
#include <hip/hip_runtime.h>
#include <math.h>

// Problem constants (match reference)
constexpr int   B       = 2048;
constexpr int   P       = 4;
constexpr int   D       = 256;       // K of the GEMM
constexpr int   NNEG    = 32768;
constexpr int   NTILES  = NNEG / 64; // per-row exp2-sum partials (64-col patches)
constexpr float TEMP    = 0.05f;
constexpr float ALPHA   = 0.1f;
constexpr float EPS     = 1e-12f;
constexpr float INV_T   = 1.0f / TEMP;
// A-side rows are pre-scaled by (1/T)*log2(e) so the MFMA accumulator is
// directly q = sim/T * log2(e), and exp(sim/T) = exp2(q).  |q| <= ~30 so no
// max-tracking is needed (exp2 stays in fp32 range).
constexpr float SCALE_Q = 28.853900817779268f;

typedef __bf16 bf16x8 __attribute__((ext_vector_type(8)));
typedef float  f32x4  __attribute__((ext_vector_type(4)));

// fp32 -> bf16 (RNE), bit-level
__device__ inline unsigned short f2bf(float f) {
  unsigned int u = __float_as_uint(f);
  u = (u + 0x7fffu + ((u >> 16) & 1u)) >> 16;
  return (unsigned short)u;
}

// ---------------------------------------------------------------------------
// FRAGMENT-MAJOR layout (16-row panels, verified rounds 7-12): element (row,k)
// of a [R x 256] bf16 matrix lives at ushort index
//   p*4096 + c*512 + q*128 + r*8 + j
// where p=row>>4, r=row&15, c=k>>5, q=(k>>3)&3, j=k&7.
// Panel p is a CONTIGUOUS 8 KB block.  Fragment (p,c) = 1024 contiguous
// bytes; MFMA lane l=r+16q reads its 16 B at byte offset l*16.
// k is identically permuted for A and B, so the dot product is unchanged.
// ---------------------------------------------------------------------------

// ---------------------------------------------------------------------------
// Kernel 1 (fused prep), round-13 rework.  Two block ranges:
//
//  [0, NPANEL)      : PANEL blocks.  One block per 16-row panel (A: 128
//    panels w/ SCALE_Q, N: 2048 panels).  Phase 1: wave w normalizes rows
//    w*4..w*4+3 into an LDS tile (row stride 264 ushorts: 16 B-aligned rows,
//    <=2-way banks).  Phase 2 (after barrier): thread t emits panel ushorts
//    [t*16, t*16+16) -- the panel's frag-major image is written as ONE
//    contiguous 8 KB stream (2 KB per wave per store step).
//    This replaces round 7-12's scattered 8 B stores (~8x write-amplified,
//    ~64 touched lines per wave) with perfectly coalesced dwordx4 streams.
//    Gather from LDS: i=t*16+m -> r=(2t+(m>>3))&15, k=(t>>5)*32+((t>>3)&3)*8
//    + (m&7) -> two 16 B LDS reads per thread.
//
//  [NPANEL, NPANEL+B*P/4) : possim blocks, one wave per (b,j) pair (exact
//    fp32), unchanged.
// ---------------------------------------------------------------------------
constexpr int NPANEL = (B + NNEG) / 16;      // 128 + 2048 = 2176
constexpr int LSTR   = 264;                  // LDS row stride in ushorts

__global__ __launch_bounds__(256) void prep_kernel(
    const float* __restrict__ a,
    const float* __restrict__ pzx,
    const float* __restrict__ n,
    unsigned short* __restrict__ a_bf,
    unsigned short* __restrict__ n_bf,
    float* __restrict__ pos_sim,
    float* __restrict__ loss_acc,
    unsigned int* __restrict__ ticket) {
  if (blockIdx.x == 0 && threadIdx.x == 0) { *loss_acc = 0.0f; *ticket = 0u; }
  const int id   = blockIdx.x;
  const int tid  = threadIdx.x;
  const int wave = tid >> 6;
  const int lane = tid & 63;

  if (id < NPANEL) {
    __shared__ __align__(16) unsigned short sm[16 * LSTR];  // 8448 B
    const float* src; unsigned short* dst; int prow; float post;
    if (id < B / 16) { src = a; dst = a_bf; prow = id;          post = SCALE_Q; }
    else             { src = n; dst = n_bf; prow = id - B / 16; post = 1.0f; }

    // Phase 1: wave w normalizes rows w*4 .. w*4+3 of the panel into LDS.
#pragma unroll
    for (int rr = 0; rr < 4; rr++) {
      const int r = wave * 4 + rr;                       // 0..15
      float4 v = ((const float4*)(src + ((size_t)prow * 16 + r) * D))[lane];
      float ss = v.x * v.x + v.y * v.y + v.z * v.z + v.w * v.w;
#pragma unroll
      for (int off = 32; off > 0; off >>= 1) ss += __shfl_xor(ss, off, 64);
      float inv = post / fmaxf(sqrtf(ss), EPS);
      ushort4 o;
      o.x = f2bf(v.x * inv); o.y = f2bf(v.y * inv);
      o.z = f2bf(v.z * inv); o.w = f2bf(v.w * inv);
      *(ushort4*)&sm[r * LSTR + lane * 4] = o;
    }
    __syncthreads();

    // Phase 2: thread t writes panel ushorts [t*16, +16) -- contiguous 8 KB.
    const int r1 = (2 * tid) & 15;
    const int r2 = (2 * tid + 1) & 15;
    const int k0 = (tid >> 5) * 32 + ((tid >> 3) & 3) * 8;
    uint4 lo = *(const uint4*)&sm[r1 * LSTR + k0];
    uint4 hi = *(const uint4*)&sm[r2 * LSTR + k0];
    uint4* outp = (uint4*)(dst + (size_t)prow * 4096 + tid * 16);
    outp[0] = lo;
    outp[1] = hi;
  } else {
    int pw = (id - NPANEL) * 4 + wave;   // 0..B*P-1
    if (pw >= B * P) return;
    int b = pw >> 2;                     // P == 4
    float4 av = ((const float4*)(a + (size_t)b * D))[lane];
    float4 pv = ((const float4*)(pzx + (size_t)pw * D))[lane];
    float d  = av.x * pv.x + av.y * pv.y + av.z * pv.z + av.w * pv.w;
    float sa = av.x * av.x + av.y * av.y + av.z * av.z + av.w * av.w;
    float sp = pv.x * pv.x + pv.y * pv.y + pv.z * pv.z + pv.w * pv.w;
#pragma unroll
    for (int off = 32; off > 0; off >>= 1) {
      d  += __shfl_xor(d, off, 64);
      sa += __shfl_xor(sa, off, 64);
      sp += __shfl_xor(sp, off, 64);
    }
    if (lane == 0) {
      float inva = 1.0f / fmaxf(sqrtf(sa), EPS);
      float invp = 1.0f / fmaxf(sqrtf(sp), EPS);
      pos_sim[pw] = d * inva * invp * INV_T;
    }
  }
}

// ---------------------------------------------------------------------------
// Kernel 2: bf16 MFMA GEMM (16x16x32) fused with exp2-sum partials.
// EXACT ROUND-9 STRUCTURE (measured best: 44 us, MfmaUtil 30%):
// Block = 64 x 256 tile, 4 waves; wave w owns a 64x64 col-patch (4x4 of
// 16x16 tiles, acc = 16 x f32x4 = 64 AGPR).  A-tile (32 frags = 32 KB)
// staged into LDS ONCE via global_load_lds, then the kernel's ONLY barrier;
// zero barriers in the K-loop.  B fragments depth-1 ping-pong direct from
// frag-major global.  Depth-2 (R12) and 8-wave TLP (R11) both measured
// SLOWER; 32x32x16 shape (R10) much slower.  XCD swizzle: id&7 -> xcd owns
// a 16-nblk strip (2 MB of N) + all of A (1 MB) < 4 MB per-XCD L2.
// ---------------------------------------------------------------------------
constexpr int BM = 64, BN = 256;

__global__ __launch_bounds__(256, 4) void negsim_mfma_kernel(
    const unsigned short* __restrict__ Af,   // frag-major [B][256]
    const unsigned short* __restrict__ Nf,   // frag-major [NNEG][256]
    float* __restrict__ part_s) {            // [B][NTILES]
  __shared__ __align__(16) unsigned short As[32 * 512];  // 32 KB

  const int tid  = threadIdx.x;
  const int wave = tid >> 6;   // 0..3 = N-direction 64-col patch
  const int lane = tid & 63;

  const int id   = blockIdx.x;
  const int xcd  = id & 7;
  const int j    = id >> 3;              // 0..511
  const int nblk = xcd * 16 + (j & 15);  // 0..127
  const int mblk = j >> 4;               // 0..31
  const int m0   = mblk * BM;
  const int n0   = nblk * BN;

  // ---- stage A-tile (32 frags) once: wave stages frags [wave*8, +8) ----
#pragma unroll
  for (int t = 0; t < 8; t++) {
    const int f = wave * 8 + t;        // 0..31
    const int c = f >> 2, p = f & 3;
    __builtin_amdgcn_global_load_lds(
        (const __attribute__((address_space(1))) unsigned int*)
            (Af + (size_t)((m0 >> 4) + p) * 4096 + c * 512 + lane * 8),
        (__attribute__((address_space(3))) unsigned int*)(As + f * 512 + lane * 8),
        16, 0, 0);
  }
  __syncthreads();   // the kernel's only barrier (drains the staging loads)

  // ---- K-loop: A from LDS, B ping-pong direct from global ----
  const unsigned short* Bp = Nf + (size_t)((n0 >> 4) + wave * 4) * 4096 + lane * 8;

  f32x4 acc[4][4] = {};
  bf16x8 b0[4], b1[4];

#pragma unroll
  for (int ni = 0; ni < 4; ni++)
    b0[ni] = *(const bf16x8*)(Bp + (size_t)ni * 4096);

#pragma unroll
  for (int c = 0; c < 8; c += 2) {
#pragma unroll
    for (int ni = 0; ni < 4; ni++)
      b1[ni] = *(const bf16x8*)(Bp + (size_t)ni * 4096 + (c + 1) * 512);
    {
      bf16x8 af[4];
#pragma unroll
      for (int mi = 0; mi < 4; mi++)
        af[mi] = *(const bf16x8*)&As[(c * 4 + mi) * 512 + lane * 8];
#pragma unroll
      for (int mi = 0; mi < 4; mi++)
#pragma unroll
        for (int ni = 0; ni < 4; ni++)
          acc[mi][ni] = __builtin_amdgcn_mfma_f32_16x16x32_bf16(
              af[mi], b0[ni], acc[mi][ni], 0, 0, 0);
    }
    if (c + 2 < 8) {
#pragma unroll
      for (int ni = 0; ni < 4; ni++)
        b0[ni] = *(const bf16x8*)(Bp + (size_t)ni * 4096 + (c + 2) * 512);
    }
    {
      bf16x8 af[4];
#pragma unroll
      for (int mi = 0; mi < 4; mi++)
        af[mi] = *(const bf16x8*)&As[((c + 1) * 4 + mi) * 512 + lane * 8];
#pragma unroll
      for (int mi = 0; mi < 4; mi++)
#pragma unroll
        for (int ni = 0; ni < 4; ni++)
          acc[mi][ni] = __builtin_amdgcn_mfma_f32_16x16x32_bf16(
              af[mi], b1[ni], acc[mi][ni], 0, 0, 0);
    }
  }

  // Epilogue: C/D layout row = mi*16 + (lane>>4)*4 + rr, col = ni*16+(lane&15).
#pragma unroll
  for (int mi = 0; mi < 4; mi++) {
#pragma unroll
    for (int rr = 0; rr < 4; rr++) {
      float s = __builtin_amdgcn_exp2f(acc[mi][0][rr]) +
                __builtin_amdgcn_exp2f(acc[mi][1][rr]) +
                __builtin_amdgcn_exp2f(acc[mi][2][rr]) +
                __builtin_amdgcn_exp2f(acc[mi][3][rr]);
#pragma unroll
      for (int off = 1; off < 16; off <<= 1) s += __shfl_xor(s, off, 64);
      if ((lane & 15) == 0) {
        int row = m0 + mi * 16 + (lane >> 4) * 4 + rr;
        part_s[(size_t)row * NTILES + (nblk * 4 + wave)] = s;
      }
    }
  }
}

// ---------------------------------------------------------------------------
// Kernel 3: per-anchor loss + final reduce.  128 blocks x 256 threads; each
// 16-lane group handles one anchor (16-way split of the 512-partial sum).
// One atomicAdd per block (128 total) + ticket; last block writes out[0].
// ---------------------------------------------------------------------------
__global__ void loss_kernel(const float* __restrict__ part_s,
                            const float* __restrict__ pos_sim,
                            const int* __restrict__ counts,
                            float* __restrict__ loss_acc,
                            unsigned int* __restrict__ ticket,
                            float* __restrict__ out) {
  const int tid = threadIdx.x;
  const int b   = blockIdx.x * 16 + (tid >> 4);
  const int sub = tid & 15;
  const float* ps = part_s + (size_t)b * NTILES;
  float s = 0.0f;
#pragma unroll
  for (int i = 0; i < NTILES / 16; i++) s += ps[sub + i * 16];
  s += __shfl_xor(s, 1, 64);
  s += __shfl_xor(s, 2, 64);
  s += __shfl_xor(s, 4, 64);
  s += __shfl_xor(s, 8, 64);   // 16-lane group now holds full S

  float acc = 0.0f;
  if (sub == 0) {
    float L = logf(s);  // neg_lse in natural-log units
    float p0 = pos_sim[b * P + 0], p1 = pos_sim[b * P + 1];
    float p2 = pos_sim[b * P + 2], p3 = pos_sim[b * P + 3];
    int cnt = counts[b];
    float pj[P] = {p0, p1, p2, p3};
#pragma unroll
    for (int jj = 0; jj < P; jj++) {
      if (jj < cnt) {
        float hi = fmaxf(pj[jj], L), lo = fminf(pj[jj], L);
        acc += hi + log1pf(__expf(lo - hi)) - pj[jj];
      }
    }
    float mp = fmaxf(fmaxf(p0, p1), fmaxf(p2, p3));
    float e0 = __expf(p0 - mp), e1 = __expf(p1 - mp);
    float e2 = __expf(p2 - mp), e3 = __expf(p3 - mp);
    float se = e0 + e1 + e2 + e3;
    float wps = (e0 * p0 + e1 * p1 + e2 * p2 + e3 * p3) / se;
    if (cnt > 1) {
      float hi = fmaxf(wps, L), lo = fminf(wps, L);
      acc += ALPHA * (hi + log1pf(__expf(lo - hi)) - wps);
    }
  }
  // block reduce (only sub==0 lanes carry nonzero)
#pragma unroll
  for (int off = 32; off > 0; off >>= 1) acc += __shfl_xor(acc, off, 64);
  __shared__ float sa[4];
  int wid = tid >> 6, lane = tid & 63;
  if (lane == 0) sa[wid] = acc;
  __syncthreads();
  if (tid == 0) {
    atomicAdd(loss_acc, sa[0] + sa[1] + sa[2] + sa[3]);
    __threadfence();
    unsigned int t = atomicAdd(ticket, 1u);
    if (t == (unsigned int)gridDim.x - 1u) {
      float total = atomicAdd(loss_acc, 0.0f);  // atomic read-back
      out[0] = total / (float)B;
    }
  }
}

// ---------------------------------------------------------------------------
extern "C" void kernel_launch(void* const* d_in, const int* in_sizes, int n_in,
                              void* d_out, int out_size, void* d_ws,
                              size_t ws_size, hipStream_t stream) {
  const float* anc    = (const float*)d_in[0];
  const float* pos    = (const float*)d_in[1];
  const float* neg    = (const float*)d_in[2];
  const int*   counts = (const int*)d_in[3];
  float* out = (float*)d_out;

  // Workspace layout: ~21.1 MB
  unsigned short* a_bf = (unsigned short*)d_ws;          // B*D      (1 MB)
  unsigned short* n_bf = a_bf + (size_t)B * D;           // NNEG*D   (16 MB)
  float* part_s  = (float*)(n_bf + (size_t)NNEG * D);    // B*NTILES (4 MB)
  float* pos_sim = part_s + (size_t)B * NTILES;          // B*P
  float* loss_acc = pos_sim + B * P;                     // 1
  unsigned int* ticket = (unsigned int*)(loss_acc + 1);  // 1

  // 2176 panel blocks + 2048 possim blocks
  prep_kernel<<<NPANEL + B * P / 4, 256, 0, stream>>>(
      anc, pos, neg, a_bf, n_bf, pos_sim, loss_acc, ticket);

  negsim_mfma_kernel<<<4096, 256, 0, stream>>>(a_bf, n_bf, part_s);

  loss_kernel<<<B / 16, 256, 0, stream>>>(part_s, pos_sim, counts,
                                          loss_acc, ticket, out);
}

// Round 14
// 126.242 us; speedup vs baseline: 1.2509x; 1.0886x over previous
//
#include <hip/hip_runtime.h>
#include <math.h>

// Problem constants (match reference)
constexpr int   B       = 2048;
constexpr int   P       = 4;
constexpr int   D       = 256;       // K of the GEMM
constexpr int   NNEG    = 32768;
constexpr int   NTILES  = NNEG / 64; // per-row exp2-sum partials (64-col patches)
constexpr float TEMP    = 0.05f;
constexpr float ALPHA   = 0.1f;
constexpr float EPS     = 1e-12f;
constexpr float INV_T   = 1.0f / TEMP;
// A-side rows are pre-scaled by (1/T)*log2(e) so the MFMA accumulator is
// directly q = sim/T * log2(e), and exp(sim/T) = exp2(q).  |q| <= ~30 so no
// max-tracking is needed, and 28.85 << 448 (fp8 e4m3 max) so the scale is
// fp8-safe; fp relative precision is scale-invariant.
constexpr float SCALE_Q = 28.853900817779268f;

typedef float f32x4 __attribute__((ext_vector_type(4)));

// fp32 -> bf16 (RNE), bit-level
__device__ inline unsigned short f2bf(float f) {
  unsigned int u = __float_as_uint(f);
  u = (u + 0x7fffu + ((u >> 16) & 1u)) >> 16;
  return (unsigned short)u;
}
// bf16 bits -> fp32
__device__ inline float bf2f(unsigned short u) {
  return __uint_as_float((unsigned int)u << 16);
}

// ---------------------------------------------------------------------------
// FP8 FRAGMENT-MAJOR layout: element (row, k) of a [R x 256] fp8 matrix is at
// BYTE index  p*4096 + c*512 + q*128 + r*8 + j
// where p=row>>4 (16-row panel, 4096 B contiguous), r=row&15, c=k>>5
// (32-k chunk), q=(k>>3)&3, j=k&7.  Fragment (p,c) = 512 contiguous bytes;
// MFMA fp8 16x16x32 lane l=r+16q reads its 8 B at byte offset l*8 (operand
// layout m=lane&15, k=(lane>>4)*8+j — same pattern as the verified bf16
// 16x16x32 mapping, 1 B/element).  k identically permuted for A and B.
// ---------------------------------------------------------------------------

// ---------------------------------------------------------------------------
// Kernel 1 (fused prep).  Two block ranges:
//  [0, NPANEL): one block per 16-row panel.  Phase 1: wave w normalizes rows
//    w*4..w*4+3 into an LDS bf16 tile (stride 264).  Phase 2 (after barrier):
//    thread t converts to fp8 and writes panel BYTES [t*16,+16) — the 4 KB
//    fp8 panel image is one contiguous coalesced stream.
//    Gather: byte i=t*16+m -> r=(2t+(m>>3))&15, k=(t>>5)*32+((t>>3)&3)*8+(m&7)
//    (first 8 bytes row r1, next 8 row r2, 8 consecutive k each).
//  [NPANEL, ...): possim, one wave per (b,j) pair, exact fp32.
// ---------------------------------------------------------------------------
constexpr int NPANEL = (B + NNEG) / 16;      // 2176
constexpr int LSTR   = 264;                  // LDS row stride in ushorts

__global__ __launch_bounds__(256) void prep_kernel(
    const float* __restrict__ a,
    const float* __restrict__ pzx,
    const float* __restrict__ n,
    unsigned char* __restrict__ a_f8,
    unsigned char* __restrict__ n_f8,
    float* __restrict__ pos_sim,
    float* __restrict__ loss_acc,
    unsigned int* __restrict__ ticket) {
  if (blockIdx.x == 0 && threadIdx.x == 0) { *loss_acc = 0.0f; *ticket = 0u; }
  const int id   = blockIdx.x;
  const int tid  = threadIdx.x;
  const int wave = tid >> 6;
  const int lane = tid & 63;

  if (id < NPANEL) {
    __shared__ __align__(16) unsigned short sm[16 * LSTR];
    const float* src; unsigned char* dst; int prow; float post;
    if (id < B / 16) { src = a; dst = a_f8; prow = id;          post = SCALE_Q; }
    else             { src = n; dst = n_f8; prow = id - B / 16; post = 1.0f; }

    // Phase 1: normalize rows into LDS (bf16).
#pragma unroll
    for (int rr = 0; rr < 4; rr++) {
      const int r = wave * 4 + rr;                       // 0..15
      float4 v = ((const float4*)(src + ((size_t)prow * 16 + r) * D))[lane];
      float ss = v.x * v.x + v.y * v.y + v.z * v.z + v.w * v.w;
#pragma unroll
      for (int off = 32; off > 0; off >>= 1) ss += __shfl_xor(ss, off, 64);
      float inv = post / fmaxf(sqrtf(ss), EPS);
      ushort4 o;
      o.x = f2bf(v.x * inv); o.y = f2bf(v.y * inv);
      o.z = f2bf(v.z * inv); o.w = f2bf(v.w * inv);
      *(ushort4*)&sm[r * LSTR + lane * 4] = o;
    }
    __syncthreads();

    // Phase 2: thread t emits fp8 panel bytes [t*16,+16) as one uint4 store.
    const int r1 = (2 * tid) & 15;
    const int r2 = (2 * tid + 1) & 15;
    const int k0 = (tid >> 5) * 32 + ((tid >> 3) & 3) * 8;
    const unsigned short* s1 = &sm[r1 * LSTR + k0];
    const unsigned short* s2 = &sm[r2 * LSTR + k0];
    uint4 ov;
    {
      int w0 = __builtin_amdgcn_cvt_pk_fp8_f32(bf2f(s1[0]), bf2f(s1[1]), 0, false);
      w0     = __builtin_amdgcn_cvt_pk_fp8_f32(bf2f(s1[2]), bf2f(s1[3]), w0, true);
      int w1 = __builtin_amdgcn_cvt_pk_fp8_f32(bf2f(s1[4]), bf2f(s1[5]), 0, false);
      w1     = __builtin_amdgcn_cvt_pk_fp8_f32(bf2f(s1[6]), bf2f(s1[7]), w1, true);
      int w2 = __builtin_amdgcn_cvt_pk_fp8_f32(bf2f(s2[0]), bf2f(s2[1]), 0, false);
      w2     = __builtin_amdgcn_cvt_pk_fp8_f32(bf2f(s2[2]), bf2f(s2[3]), w2, true);
      int w3 = __builtin_amdgcn_cvt_pk_fp8_f32(bf2f(s2[4]), bf2f(s2[5]), 0, false);
      w3     = __builtin_amdgcn_cvt_pk_fp8_f32(bf2f(s2[6]), bf2f(s2[7]), w3, true);
      ov.x = (unsigned)w0; ov.y = (unsigned)w1;
      ov.z = (unsigned)w2; ov.w = (unsigned)w3;
    }
    *(uint4*)(dst + (size_t)prow * 4096 + tid * 16) = ov;
  } else {
    int pw = (id - NPANEL) * 4 + wave;   // 0..B*P-1
    if (pw >= B * P) return;
    int b = pw >> 2;                     // P == 4
    float4 av = ((const float4*)(a + (size_t)b * D))[lane];
    float4 pv = ((const float4*)(pzx + (size_t)pw * D))[lane];
    float d  = av.x * pv.x + av.y * pv.y + av.z * pv.z + av.w * pv.w;
    float sa = av.x * av.x + av.y * av.y + av.z * av.z + av.w * av.w;
    float sp = pv.x * pv.x + pv.y * pv.y + pv.z * pv.z + pv.w * pv.w;
#pragma unroll
    for (int off = 32; off > 0; off >>= 1) {
      d  += __shfl_xor(d, off, 64);
      sa += __shfl_xor(sa, off, 64);
      sp += __shfl_xor(sp, off, 64);
    }
    if (lane == 0) {
      float inva = 1.0f / fmaxf(sqrtf(sa), EPS);
      float invp = 1.0f / fmaxf(sqrtf(sp), EPS);
      pos_sim[pw] = d * inva * invp * INV_T;
    }
  }
}

// ---------------------------------------------------------------------------
// Kernel 2: fp8 MFMA GEMM (16x16x32_fp8_fp8, bf16-rate but HALF the bytes)
// fused with exp2-sum partials.  Round-9 proven skeleton:
// Block = 64x256 tile, 4 waves; wave w owns a 64x64 col-patch (4x4 of 16x16
// tiles, acc = 64 AGPR).  A-tile now 16 KB (32 frags x 512 B, PANEL-major:
// frag (p,c) at (p*8+c)*512 so each global_load_lds instruction stages 1 KB
// = 2 chunks contiguous in both global and LDS; 4 instr/wave).  One barrier
// total; zero barriers in the K-loop.  B fragments 8 B/lane dwordx2,
// depth-1 ping-pong (R12 depth-2 and R11 8-wave TLP both measured slower).
// XCD swizzle: id&7 -> xcd owns 16-nblk strip (1 MB N fp8) + A (0.5 MB).
// Epilogue: acc holds q = sim/T*log2e; 16-lane shuffle exp2-sum -> part_s.
// ---------------------------------------------------------------------------
constexpr int BM = 64, BN = 256;

__global__ __launch_bounds__(256, 4) void negsim_mfma_kernel(
    const unsigned char* __restrict__ Af,   // fp8 frag-major [B][256]
    const unsigned char* __restrict__ Nf,   // fp8 frag-major [NNEG][256]
    float* __restrict__ part_s) {           // [B][NTILES]
  __shared__ __align__(16) unsigned char As[32 * 512];  // 16 KB

  const int tid  = threadIdx.x;
  const int wave = tid >> 6;   // 0..3 = N-direction 64-col patch
  const int lane = tid & 63;

  const int id   = blockIdx.x;
  const int xcd  = id & 7;
  const int j    = id >> 3;              // 0..511
  const int nblk = xcd * 16 + (j & 15);  // 0..127
  const int mblk = j >> 4;               // 0..31
  const int m0   = mblk * BM;
  const int n0   = nblk * BN;

  // ---- stage A-tile once: instr s = wave*4+t covers LDS [s*1024, +1024)
  //      = frags (p = wave, c = 2t, 2t+1); contiguous in global too. ----
#pragma unroll
  for (int t = 0; t < 4; t++) {
    const int s = wave * 4 + t;
    __builtin_amdgcn_global_load_lds(
        (const __attribute__((address_space(1))) unsigned int*)
            (Af + (size_t)((m0 >> 4) + wave) * 4096 + t * 1024 + lane * 16),
        (__attribute__((address_space(3))) unsigned int*)(As + s * 1024 + lane * 16),
        16, 0, 0);
  }
  __syncthreads();   // the kernel's only barrier (drains the staging loads)

  // ---- K-loop: A from LDS (b64 reads), B ping-pong direct from global ----
  const unsigned char* Bp = Nf + (size_t)((n0 >> 4) + wave * 4) * 4096 + lane * 8;

  f32x4 acc[4][4] = {};
  long b0[4], b1[4];

#pragma unroll
  for (int ni = 0; ni < 4; ni++)
    b0[ni] = *(const long*)(Bp + (size_t)ni * 4096);

#pragma unroll
  for (int c = 0; c < 8; c += 2) {
#pragma unroll
    for (int ni = 0; ni < 4; ni++)
      b1[ni] = *(const long*)(Bp + (size_t)ni * 4096 + (c + 1) * 512);
    {
      long af[4];
#pragma unroll
      for (int mi = 0; mi < 4; mi++)
        af[mi] = *(const long*)&As[(mi * 8 + c) * 512 + lane * 8];
#pragma unroll
      for (int mi = 0; mi < 4; mi++)
#pragma unroll
        for (int ni = 0; ni < 4; ni++)
          acc[mi][ni] = __builtin_amdgcn_mfma_f32_16x16x32_fp8_fp8(
              af[mi], b0[ni], acc[mi][ni], 0, 0, 0);
    }
    if (c + 2 < 8) {
#pragma unroll
      for (int ni = 0; ni < 4; ni++)
        b0[ni] = *(const long*)(Bp + (size_t)ni * 4096 + (c + 2) * 512);
    }
    {
      long af[4];
#pragma unroll
      for (int mi = 0; mi < 4; mi++)
        af[mi] = *(const long*)&As[(mi * 8 + c + 1) * 512 + lane * 8];
#pragma unroll
      for (int mi = 0; mi < 4; mi++)
#pragma unroll
        for (int ni = 0; ni < 4; ni++)
          acc[mi][ni] = __builtin_amdgcn_mfma_f32_16x16x32_fp8_fp8(
              af[mi], b1[ni], acc[mi][ni], 0, 0, 0);
    }
  }

  // Epilogue: C/D layout row = mi*16 + (lane>>4)*4 + rr, col = ni*16+(lane&15)
  // (dtype-independent on gfx950).
#pragma unroll
  for (int mi = 0; mi < 4; mi++) {
#pragma unroll
    for (int rr = 0; rr < 4; rr++) {
      float s = __builtin_amdgcn_exp2f(acc[mi][0][rr]) +
                __builtin_amdgcn_exp2f(acc[mi][1][rr]) +
                __builtin_amdgcn_exp2f(acc[mi][2][rr]) +
                __builtin_amdgcn_exp2f(acc[mi][3][rr]);
#pragma unroll
      for (int off = 1; off < 16; off <<= 1) s += __shfl_xor(s, off, 64);
      if ((lane & 15) == 0) {
        int row = m0 + mi * 16 + (lane >> 4) * 4 + rr;
        part_s[(size_t)row * NTILES + (nblk * 4 + wave)] = s;
      }
    }
  }
}

// ---------------------------------------------------------------------------
// Kernel 3: per-anchor loss + final reduce.  128 blocks x 256 threads; each
// 16-lane group handles one anchor.  One atomicAdd per block + ticket; last
// block writes out[0].
// ---------------------------------------------------------------------------
__global__ void loss_kernel(const float* __restrict__ part_s,
                            const float* __restrict__ pos_sim,
                            const int* __restrict__ counts,
                            float* __restrict__ loss_acc,
                            unsigned int* __restrict__ ticket,
                            float* __restrict__ out) {
  const int tid = threadIdx.x;
  const int b   = blockIdx.x * 16 + (tid >> 4);
  const int sub = tid & 15;
  const float* ps = part_s + (size_t)b * NTILES;
  float s = 0.0f;
#pragma unroll
  for (int i = 0; i < NTILES / 16; i++) s += ps[sub + i * 16];
  s += __shfl_xor(s, 1, 64);
  s += __shfl_xor(s, 2, 64);
  s += __shfl_xor(s, 4, 64);
  s += __shfl_xor(s, 8, 64);   // 16-lane group now holds full S

  float acc = 0.0f;
  if (sub == 0) {
    float L = logf(s);  // neg_lse in natural-log units
    float p0 = pos_sim[b * P + 0], p1 = pos_sim[b * P + 1];
    float p2 = pos_sim[b * P + 2], p3 = pos_sim[b * P + 3];
    int cnt = counts[b];
    float pj[P] = {p0, p1, p2, p3};
#pragma unroll
    for (int jj = 0; jj < P; jj++) {
      if (jj < cnt) {
        float hi = fmaxf(pj[jj], L), lo = fminf(pj[jj], L);
        acc += hi + log1pf(__expf(lo - hi)) - pj[jj];
      }
    }
    float mp = fmaxf(fmaxf(p0, p1), fmaxf(p2, p3));
    float e0 = __expf(p0 - mp), e1 = __expf(p1 - mp);
    float e2 = __expf(p2 - mp), e3 = __expf(p3 - mp);
    float se = e0 + e1 + e2 + e3;
    float wps = (e0 * p0 + e1 * p1 + e2 * p2 + e3 * p3) / se;
    if (cnt > 1) {
      float hi = fmaxf(wps, L), lo = fminf(wps, L);
      acc += ALPHA * (hi + log1pf(__expf(lo - hi)) - wps);
    }
  }
#pragma unroll
  for (int off = 32; off > 0; off >>= 1) acc += __shfl_xor(acc, off, 64);
  __shared__ float sa[4];
  int wid = tid >> 6, lane = tid & 63;
  if (lane == 0) sa[wid] = acc;
  __syncthreads();
  if (tid == 0) {
    atomicAdd(loss_acc, sa[0] + sa[1] + sa[2] + sa[3]);
    __threadfence();
    unsigned int t = atomicAdd(ticket, 1u);
    if (t == (unsigned int)gridDim.x - 1u) {
      float total = atomicAdd(loss_acc, 0.0f);  // atomic read-back
      out[0] = total / (float)B;
    }
  }
}

// ---------------------------------------------------------------------------
extern "C" void kernel_launch(void* const* d_in, const int* in_sizes, int n_in,
                              void* d_out, int out_size, void* d_ws,
                              size_t ws_size, hipStream_t stream) {
  const float* anc    = (const float*)d_in[0];
  const float* pos    = (const float*)d_in[1];
  const float* neg    = (const float*)d_in[2];
  const int*   counts = (const int*)d_in[3];
  float* out = (float*)d_out;

  // Workspace layout: ~12.6 MB
  unsigned char* a_f8 = (unsigned char*)d_ws;            // B*D      (0.5 MB)
  unsigned char* n_f8 = a_f8 + (size_t)B * D;            // NNEG*D   (8 MB)
  float* part_s  = (float*)(n_f8 + (size_t)NNEG * D);    // B*NTILES (4 MB)
  float* pos_sim = part_s + (size_t)B * NTILES;          // B*P
  float* loss_acc = pos_sim + B * P;                     // 1
  unsigned int* ticket = (unsigned int*)(loss_acc + 1);  // 1

  // 2176 panel blocks + 2048 possim blocks
  prep_kernel<<<NPANEL + B * P / 4, 256, 0, stream>>>(
      anc, pos, neg, a_f8, n_f8, pos_sim, loss_acc, ticket);

  negsim_mfma_kernel<<<4096, 256, 0, stream>>>(a_f8, n_f8, part_s);

  loss_kernel<<<B / 16, 256, 0, stream>>>(part_s, pos_sim, counts,
                                          loss_acc, ticket, out);
}